// Round 1
// baseline (4865.208 us; speedup 1.0000x reference)
//
#include <hip/hip_runtime.h>
#include <cstdint>
#include <cstddef>

typedef __attribute__((ext_vector_type(8))) __bf16 bf16x8;
typedef __attribute__((ext_vector_type(4))) float f32x4;

static constexpr int kNS   = 8192;
static constexpr int kNW   = 65536;
static constexpr int kNSEC = 1024;
static constexpr int kEW   = 131072;
static constexpr int kES   = 262144;
static constexpr int kESEC = 16384;

__device__ __forceinline__ float eluf(float x)  { return x > 0.f ? x : (__expf(x) - 1.f); }
__device__ __forceinline__ float sigmf(float x) { return 1.f / (1.f + __expf(-x)); }

// ---------------------------------------------------------------------------
// Weight convert + transpose: W[K][N] f32 -> Wt[N][KP] bf16 (zero-pad k>=K)
// ---------------------------------------------------------------------------
__global__ __launch_bounds__(256) void conv_transpose(const float* __restrict__ W, int K, int N,
                                                      __bf16* __restrict__ Wt, int KP) {
  __shared__ float t[32][33];
  const int nb = blockIdx.x * 32, kb = blockIdx.y * 32;
  const int tx = threadIdx.x & 31, ty = threadIdx.x >> 5;
#pragma unroll
  for (int i = ty; i < 32; i += 8) {
    const int k = kb + i;
    t[i][tx] = (k < K) ? W[(long)k * N + nb + tx] : 0.f;
  }
  __syncthreads();
#pragma unroll
  for (int i = ty; i < 32; i += 8) {
    Wt[(long)(nb + i) * KP + kb + tx] = (__bf16)t[tx][i];
  }
}

__global__ __launch_bounds__(256) void conv_bf(const float* __restrict__ in, __bf16* __restrict__ outb, long n) {
  long i = (long)blockIdx.x * blockDim.x + threadIdx.x;
  if (i < n) outb[i] = (__bf16)in[i];
}

// ---------------------------------------------------------------------------
// Head vectors: out[h][k] = sum_c W[k][h*640+c] * a[h][c]   (k<Kd, pad->0)
// ---------------------------------------------------------------------------
__global__ __launch_bounds__(256) void head_vecs(const float* __restrict__ W, const float* __restrict__ a,
                                                 float* __restrict__ outv, int Kd, int KP) {
  const int gid = blockIdx.x * blockDim.x + threadIdx.x;
  if (gid >= 8 * KP) return;
  const int h = gid / KP, k = gid - h * KP;
  float s = 0.f;
  if (k < Kd) {
    const float* wr = W + (long)k * 5120 + h * 640;
    const float* ar = a + h * 640;
    for (int c = 0; c < 640; ++c) s += wr[c] * ar[c];
  }
  outv[gid] = s;
}

// ---------------------------------------------------------------------------
// Attention logits: out[n][h] = X[n,:Kd] . vec[h,:Kd]    (1 wave per node)
// ---------------------------------------------------------------------------
__global__ __launch_bounds__(256) void att_logits(const float* __restrict__ X, int ldx, int Kd,
                                                  const float* __restrict__ vec, int KP,
                                                  float* __restrict__ outl, int N) {
  const int lane = threadIdx.x & 63;
  const int node = blockIdx.x * 4 + (threadIdx.x >> 6);
  if (node >= N) return;
  const float* xr = X + (long)node * ldx;
  float p[8];
#pragma unroll
  for (int h = 0; h < 8; ++h) p[h] = 0.f;
  for (int k = lane; k < Kd; k += 64) {
    const float xv = xr[k];
#pragma unroll
    for (int h = 0; h < 8; ++h) p[h] += xv * vec[h * KP + k];
  }
#pragma unroll
  for (int h = 0; h < 8; ++h) {
    float v = p[h];
    for (int o2 = 32; o2; o2 >>= 1) v += __shfl_down(v, o2);
    if (lane == 0) outl[(long)node * 8 + h] = v;
  }
}

// ---------------------------------------------------------------------------
// CSR build
// ---------------------------------------------------------------------------
__global__ __launch_bounds__(256) void edge_count(const int* __restrict__ dst, int E, int* __restrict__ cnt) {
  const int gid = blockIdx.x * blockDim.x + threadIdx.x;
  if (gid < E) atomicAdd(&cnt[dst[gid]], 1);
}

__global__ __launch_bounds__(1024) void scan_off(const int* __restrict__ cnt, int* __restrict__ offo) {
  __shared__ int part[1024];
  const int tid = threadIdx.x;
  const int base = tid * 8;
  int loc[8];
  int s = 0;
#pragma unroll
  for (int i = 0; i < 8; ++i) { loc[i] = s; s += cnt[base + i]; }
  part[tid] = s;
  __syncthreads();
  for (int d2 = 1; d2 < 1024; d2 <<= 1) {
    int v = (tid >= d2) ? part[tid - d2] : 0;
    __syncthreads();
    part[tid] += v;
    __syncthreads();
  }
  const int pre = (tid > 0) ? part[tid - 1] : 0;
#pragma unroll
  for (int i = 0; i < 8; ++i) offo[base + i] = pre + loc[i];
  if (tid == 1023) offo[8192] = part[1023];
}

__global__ __launch_bounds__(256) void edge_fill(const int* __restrict__ src, const int* __restrict__ dst, int E,
                                                 const int* __restrict__ offo, int* __restrict__ cur,
                                                 int* __restrict__ ssrc) {
  const int gid = blockIdx.x * blockDim.x + threadIdx.x;
  if (gid < E) {
    const int d = dst[gid];
    const int p = offo[d] + atomicAdd(&cur[d], 1);
    ssrc[p] = src[gid];
  }
}

// ---------------------------------------------------------------------------
// GAT aggregation (one block per dst sentence):
//   out[d, h*FPAD+f] = (sum_e exp(lrelu(als[src]+ald[d])) * X[src, xcol]) / (den_h + 1e-16)
//   optionally + bias, ELU.  Writes bf16 (pad channels -> 0).
// ---------------------------------------------------------------------------
template <int FPAD, int F, bool XPH, bool BIASELU>
__global__ __launch_bounds__(256) void gat_agg(const int* __restrict__ seg_off, const int* __restrict__ ssrc,
                                               const float* __restrict__ als, const float* __restrict__ ald,
                                               const float* __restrict__ X, int ldx,
                                               __bf16* __restrict__ outp, int ldo,
                                               const float* __restrict__ bias) {
  constexpr int L = (FPAD * 8) / 256;
  const int d = blockIdx.x;
  const int tid = threadIdx.x;
  const int o0 = seg_off[d], o1 = seg_off[d + 1];
  const int deg = o1 - o0;
  __shared__ float exl[64][8];
  __shared__ int ssl[64];
  __shared__ float aldd[8];
  __shared__ float den_s[8];
  if (tid < 8) { aldd[tid] = ald[(long)d * 8 + tid]; den_s[tid] = 0.f; }
  float acc[L];
  int hh[L], xc[L];
  bool vld[L];
#pragma unroll
  for (int l = 0; l < L; ++l) {
    acc[l] = 0.f;
    const int idx = tid + l * 256;
    const int h = idx / FPAD, f = idx - h * FPAD;
    hh[l] = h;
    vld[l] = (f < F);
    xc[l] = XPH ? idx : f;
  }
  __syncthreads();
  for (int base = 0; base < deg; base += 64) {
    const int nc = min(64, deg - base);
    if (tid < nc) ssl[tid] = ssrc[o0 + base + tid];
    __syncthreads();
    for (int t = tid; t < nc * 8; t += 256) {
      const int e = t >> 3, h = t & 7;
      float v = als[(long)ssl[e] * 8 + h] + aldd[h];
      v = v > 0.f ? v : 0.2f * v;
      exl[e][h] = __expf(v);
    }
    __syncthreads();
    if (tid < 8) {
      float s = 0.f;
      for (int e = 0; e < nc; ++e) s += exl[e][tid];
      den_s[tid] += s;
    }
    for (int e = 0; e < nc; ++e) {
      const float* xr = X + (long)ssl[e] * ldx;
      const float* ex8 = exl[e];
#pragma unroll
      for (int l = 0; l < L; ++l)
        if (vld[l]) acc[l] += ex8[hh[l]] * xr[xc[l]];
    }
    __syncthreads();
  }
#pragma unroll
  for (int l = 0; l < L; ++l) {
    const int idx = tid + l * 256;
    float r = acc[l] / (den_s[hh[l]] + 1e-16f);
    if constexpr (BIASELU) { r += bias[idx]; r = eluf(r); }
    outp[(long)d * ldo + idx] = (__bf16)r;
  }
}

// ---------------------------------------------------------------------------
// bf16 MFMA GEMM, C[M,N] = A[M,K] * Bt[N,K]^T  (both row-major bf16)
// 128x128 tile, BK=32, 4 waves (each 64x64 = 4x4 of 16x16x32 frags),
// double-buffered LDS, epilogue variants. Batched over blockIdx.z via strides.
// EPI: 0 store f32 | 1 bias+ELU->bf16 | 2 sigmoid-gate mix->bf16
//      3 bias->bf16 | 4 bias+residual->f32
// ---------------------------------------------------------------------------
template <int EPI>
__global__ __launch_bounds__(256) void gemm_bt(
    const __bf16* __restrict__ A, int lda, const __bf16* __restrict__ A2, int ksplit,
    const __bf16* __restrict__ Bt, int ldb, int K,
    void* __restrict__ Cout, int ldc,
    const float* __restrict__ bias,
    const __bf16* __restrict__ Xg, const __bf16* __restrict__ Yg, int ldxy,
    const float* __restrict__ Res, int ldres,
    long a_zs, long bt_zs, long c_zs, int b_zs) {
  __shared__ __bf16 sA[2][128 * 32];
  __shared__ __bf16 sB[2][128 * 32];
  const int tid = threadIdx.x;
  const int z = blockIdx.z;
  const int m0 = blockIdx.y * 128, n0 = blockIdx.x * 128;
  const __bf16* Ab = A + (long)z * a_zs;
  const __bf16* A2b = A2 ? A2 + (long)z * a_zs : nullptr;
  const __bf16* Btb = Bt + (long)z * bt_zs;
  const int lane = tid & 63;
  const int wv = tid >> 6, wr = wv >> 1, wc = wv & 1;
  const int fr = lane & 15, fq = lane >> 4;

  const int r0 = tid >> 2, kc0 = (tid & 3) * 8;  // staging chunks: rows 0..63 and 64..127
  const int r1 = r0 + 64;

  f32x4 acc[4][4];
#pragma unroll
  for (int i = 0; i < 4; ++i)
#pragma unroll
    for (int j = 0; j < 4; ++j)
#pragma unroll
      for (int r = 0; r < 4; ++r) acc[i][j][r] = 0.f;

  int aof[4], bof[4];
#pragma unroll
  for (int i = 0; i < 4; ++i) {
    aof[i] = (wr * 64 + i * 16 + fr) * 32 + fq * 8;
    bof[i] = (wc * 64 + i * 16 + fr) * 32 + fq * 8;
  }

  const int nkt = K >> 5;
  auto stage = [&](int buf, int kt) {
    const int k0 = kt * 32;
    const __bf16* As = Ab;
    int kr = k0;
    if (A2b && k0 >= ksplit) { As = A2b; kr = k0 - ksplit; }
    bf16x8 av0 = *(const bf16x8*)(As + (long)(m0 + r0) * lda + kr + kc0);
    bf16x8 av1 = *(const bf16x8*)(As + (long)(m0 + r1) * lda + kr + kc0);
    bf16x8 bv0 = *(const bf16x8*)(Btb + (long)(n0 + r0) * ldb + k0 + kc0);
    bf16x8 bv1 = *(const bf16x8*)(Btb + (long)(n0 + r1) * ldb + k0 + kc0);
    *(bf16x8*)(&sA[buf][r0 * 32 + kc0]) = av0;
    *(bf16x8*)(&sA[buf][r1 * 32 + kc0]) = av1;
    *(bf16x8*)(&sB[buf][r0 * 32 + kc0]) = bv0;
    *(bf16x8*)(&sB[buf][r1 * 32 + kc0]) = bv1;
  };

  stage(0, 0);
  for (int kt = 0; kt < nkt; ++kt) {
    const int cur = kt & 1;
    __syncthreads();
    if (kt + 1 < nkt) stage(cur ^ 1, kt + 1);
    bf16x8 af[4], bfv[4];
#pragma unroll
    for (int i = 0; i < 4; ++i) {
      af[i] = *(const bf16x8*)(&sA[cur][aof[i]]);
      bfv[i] = *(const bf16x8*)(&sB[cur][bof[i]]);
    }
#pragma unroll
    for (int i = 0; i < 4; ++i)
#pragma unroll
      for (int j = 0; j < 4; ++j)
        acc[i][j] = __builtin_amdgcn_mfma_f32_16x16x32_bf16(af[i], bfv[j], acc[i][j], 0, 0, 0);
  }

  const float* biasb = bias ? bias + (long)z * b_zs : nullptr;
#pragma unroll
  for (int i = 0; i < 4; ++i) {
#pragma unroll
    for (int j = 0; j < 4; ++j) {
#pragma unroll
      for (int r = 0; r < 4; ++r) {
        const int mm = m0 + wr * 64 + i * 16 + fq * 4 + r;
        const int nn = n0 + wc * 64 + j * 16 + fr;
        const float v = acc[i][j][r];
        const long cidx = (long)mm * ldc + nn + (long)z * c_zs;
        if constexpr (EPI == 0) {
          ((float*)Cout)[cidx] = v;
        } else if constexpr (EPI == 1) {
          ((__bf16*)Cout)[cidx] = (__bf16)eluf(v + biasb[nn]);
        } else if constexpr (EPI == 2) {
          const float zt = sigmf(v + biasb[nn]);
          const float x = (float)Xg[(long)mm * ldxy + nn];
          const float y = (float)Yg[(long)mm * ldxy + nn];
          ((__bf16*)Cout)[cidx] = (__bf16)(zt * x + (1.f - zt) * y);
        } else if constexpr (EPI == 3) {
          ((__bf16*)Cout)[cidx] = (__bf16)(v + biasb[nn]);
        } else {
          ((float*)Cout)[cidx] = v + biasb[nn] + Res[(long)mm * ldres + nn];
        }
      }
    }
  }
}

// ---------------------------------------------------------------------------
extern "C" void kernel_launch(void* const* d_in, const int* in_sizes, int n_in,
                              void* d_out, int out_size, void* d_ws, size_t ws_size,
                              hipStream_t stream) {
  (void)in_sizes; (void)n_in; (void)out_size; (void)ws_size;
  const float* Hs    = (const float*)d_in[0];
  const float* Hw    = (const float*)d_in[1];
  const float* HSec  = (const float*)d_in[2];
  const int* w2s     = (const int*)d_in[3];
  const int* s2s     = (const int*)d_in[4];
  const int* S2s     = (const int*)d_in[5];
  const float* Ww_src = (const float*)d_in[6];
  const float* Ww_dst = (const float*)d_in[7];
  const float* aw_src = (const float*)d_in[8];
  const float* aw_dst = (const float*)d_in[9];
  const float* bw     = (const float*)d_in[10];
  const float* Wss    = (const float*)d_in[11];
  const float* as_src = (const float*)d_in[12];
  const float* as_dst = (const float*)d_in[13];
  const float* bs     = (const float*)d_in[14];
  const float* WS_src = (const float*)d_in[15];
  const float* WS_dst = (const float*)d_in[16];
  const float* aS_src = (const float*)d_in[17];
  const float* aS_dst = (const float*)d_in[18];
  const float* bS     = (const float*)d_in[19];
  const float* F1_w   = (const float*)d_in[20];
  const float* F1_b   = (const float*)d_in[21];
  const float* F2_w   = (const float*)d_in[22];
  const float* F2_b   = (const float*)d_in[23];
  const float* l1_w   = (const float*)d_in[24];
  const float* l1_b   = (const float*)d_in[25];
  const float* l2_w   = (const float*)d_in[26];
  const float* l2_b   = (const float*)d_in[27];
  float* outp = (float*)d_out;

  char* ws = (char*)d_ws;
  size_t cur_off = 0;
  auto alloc = [&](size_t bytes) -> char* {
    char* p = ws + cur_off;
    cur_off = (cur_off + bytes + 255) & ~(size_t)255;
    return p;
  };

  __bf16* Wt_w  = (__bf16*)alloc((size_t)5120 * 320 * 2);
  __bf16* Wt_s  = (__bf16*)alloc((size_t)5120 * 640 * 2);
  __bf16* Wt_S  = (__bf16*)alloc((size_t)5120 * 512 * 2);
  __bf16* WtF   = (__bf16*)alloc((size_t)5120 * 10240 * 2);  // F1, then reused for F2
  __bf16* Wt_l1 = (__bf16*)alloc((size_t)2048 * 5120 * 2);
  __bf16* Wt_l2 = (__bf16*)alloc((size_t)640 * 2048 * 2);
  __bf16* HS_bf = (__bf16*)alloc((size_t)1024 * 512 * 2);
  float* v_w = (float*)alloc(8 * 320 * 4);
  float* u_w = (float*)alloc(8 * 640 * 4);
  float* v_s = (float*)alloc(8 * 640 * 4);
  float* u_s = (float*)alloc(8 * 640 * 4);
  float* v_S = (float*)alloc(8 * 512 * 4);
  float* u_S = (float*)alloc(8 * 640 * 4);
  float* alw_s = (float*)alloc((size_t)kNW * 8 * 4);
  float* alw_d = (float*)alloc((size_t)kNS * 8 * 4);
  float* als_s = (float*)alloc((size_t)kNS * 8 * 4);
  float* als_d = (float*)alloc((size_t)kNS * 8 * 4);
  float* alS_s = (float*)alloc((size_t)kNSEC * 8 * 4);
  float* alS_d = (float*)alloc((size_t)kNS * 8 * 4);
  int* csr_i  = (int*)alloc((size_t)6 * kNS * 4);  // cnt_w,cnt_s,cnt_S,cur_w,cur_s,cur_S
  int* cnt_w = csr_i, *cnt_s = csr_i + kNS, *cnt_S = csr_i + 2 * kNS;
  int* cur_w = csr_i + 3 * kNS, *cur_s = csr_i + 4 * kNS, *cur_S = csr_i + 5 * kNS;
  int* off_w = (int*)alloc((size_t)(kNS + 1) * 4);
  int* off_s = (int*)alloc((size_t)(kNS + 1) * 4);
  int* off_S = (int*)alloc((size_t)(kNS + 1) * 4);
  int* ssrc_w = (int*)alloc((size_t)kEW * 4);
  int* ssrc_s = (int*)alloc((size_t)kES * 4);
  int* ssrc_S = (int*)alloc((size_t)kESEC * 4);
  float* hs_S = (float*)alloc((size_t)1024 * 5120 * 4);
  // aliased region: agg_w+agg_s live until GAT GEMMs; U1 reuses it afterwards
  char* aggreg = alloc((size_t)kNS * 2560 * 2 + (size_t)kNS * 5120 * 2);
  __bf16* agg_w = (__bf16*)aggreg;
  __bf16* agg_s = (__bf16*)(aggreg + (size_t)kNS * 2560 * 2);
  __bf16* U1 = (__bf16*)aggreg;  // alias (agg dead by fusion1)
  __bf16* Uw = (__bf16*)alloc((size_t)kNS * 5120 * 2);
  __bf16* Us = (__bf16*)alloc((size_t)kNS * 5120 * 2);
  __bf16* US = (__bf16*)alloc((size_t)kNS * 5120 * 2);
  __bf16* U2 = Uw;  // alias (Uw dead after fusion1)
  __bf16* Tb = Us;  // alias (Us dead after fusion1)

  const dim3 b256(256);

  // 1) weight conversions/transposes
  conv_transpose<<<dim3(160, 10), b256, 0, stream>>>(Ww_src, 300, 5120, Wt_w, 320);
  conv_transpose<<<dim3(160, 20), b256, 0, stream>>>(Wss, 640, 5120, Wt_s, 640);
  conv_transpose<<<dim3(160, 16), b256, 0, stream>>>(WS_src, 512, 5120, Wt_S, 512);
  conv_transpose<<<dim3(160, 320), b256, 0, stream>>>(F1_w, 10240, 5120, WtF, 10240);
  conv_transpose<<<dim3(64, 160), b256, 0, stream>>>(l1_w, 5120, 2048, Wt_l1, 5120);
  conv_transpose<<<dim3(20, 64), b256, 0, stream>>>(l2_w, 2048, 640, Wt_l2, 2048);
  conv_bf<<<(1024 * 512 + 255) / 256, b256, 0, stream>>>(HSec, HS_bf, (long)1024 * 512);

  // 2) per-head attention vectors
  head_vecs<<<(8 * 320 + 255) / 256, b256, 0, stream>>>(Ww_src, aw_src, v_w, 300, 320);
  head_vecs<<<(8 * 640 + 255) / 256, b256, 0, stream>>>(Ww_dst, aw_dst, u_w, 640, 640);
  head_vecs<<<(8 * 640 + 255) / 256, b256, 0, stream>>>(Wss, as_src, v_s, 640, 640);
  head_vecs<<<(8 * 640 + 255) / 256, b256, 0, stream>>>(Wss, as_dst, u_s, 640, 640);
  head_vecs<<<(8 * 512 + 255) / 256, b256, 0, stream>>>(WS_src, aS_src, v_S, 512, 512);
  head_vecs<<<(8 * 640 + 255) / 256, b256, 0, stream>>>(WS_dst, aS_dst, u_S, 640, 640);

  // 3) attention logits
  att_logits<<<(kNW + 3) / 4, b256, 0, stream>>>(Hw, 300, 300, v_w, 320, alw_s, kNW);
  att_logits<<<(kNS + 3) / 4, b256, 0, stream>>>(Hs, 640, 640, u_w, 640, alw_d, kNS);
  att_logits<<<(kNS + 3) / 4, b256, 0, stream>>>(Hs, 640, 640, v_s, 640, als_s, kNS);
  att_logits<<<(kNS + 3) / 4, b256, 0, stream>>>(Hs, 640, 640, u_s, 640, als_d, kNS);
  att_logits<<<(kNSEC + 3) / 4, b256, 0, stream>>>(HSec, 512, 512, v_S, 512, alS_s, kNSEC);
  att_logits<<<(kNS + 3) / 4, b256, 0, stream>>>(Hs, 640, 640, u_S, 640, alS_d, kNS);

  // 4) CSR build (per layer)
  hipMemsetAsync(csr_i, 0, (size_t)6 * kNS * 4, stream);
  edge_count<<<(kEW + 255) / 256, b256, 0, stream>>>(w2s + kEW, kEW, cnt_w);
  edge_count<<<(kES + 255) / 256, b256, 0, stream>>>(s2s + kES, kES, cnt_s);
  edge_count<<<(kESEC + 255) / 256, b256, 0, stream>>>(S2s + kESEC, kESEC, cnt_S);
  scan_off<<<1, 1024, 0, stream>>>(cnt_w, off_w);
  scan_off<<<1, 1024, 0, stream>>>(cnt_s, off_s);
  scan_off<<<1, 1024, 0, stream>>>(cnt_S, off_S);
  edge_fill<<<(kEW + 255) / 256, b256, 0, stream>>>(w2s, w2s + kEW, kEW, off_w, cur_w, ssrc_w);
  edge_fill<<<(kES + 255) / 256, b256, 0, stream>>>(s2s, s2s + kES, kES, off_s, cur_s, ssrc_s);
  edge_fill<<<(kESEC + 255) / 256, b256, 0, stream>>>(S2s, S2s + kESEC, kESEC, off_S, cur_S, ssrc_S);

  // 5) section source transform: hs_S = HS @ WS_src  (f32 out)
  gemm_bt<0><<<dim3(40, 8, 1), b256, 0, stream>>>(
      HS_bf, 512, nullptr, 1 << 30, Wt_S, 512, 512,
      hs_S, 5120, nullptr, nullptr, nullptr, 0, nullptr, 0, 0, 0, 0, 0);

  // 6) aggregations
  gat_agg<320, 300, false, false><<<kNS, b256, 0, stream>>>(off_w, ssrc_w, alw_s, alw_d, Hw, 300, agg_w, 2560, nullptr);
  gat_agg<640, 640, false, false><<<kNS, b256, 0, stream>>>(off_s, ssrc_s, als_s, als_d, Hs, 640, agg_s, 5120, nullptr);
  gat_agg<640, 640, true, true><<<kNS, b256, 0, stream>>>(off_S, ssrc_S, alS_s, alS_d, hs_S, 5120, US, 5120, bS);

  // 7) per-head GAT output GEMMs (+bias +ELU)
  gemm_bt<1><<<dim3(5, 64, 8), b256, 0, stream>>>(
      agg_w, 2560, nullptr, 1 << 30, Wt_w, 320, 320,
      Uw, 5120, bw, nullptr, nullptr, 0, nullptr, 0, 320, (long)640 * 320, 640, 640);
  gemm_bt<1><<<dim3(5, 64, 8), b256, 0, stream>>>(
      agg_s, 5120, nullptr, 1 << 30, Wt_s, 640, 640,
      Us, 5120, bs, nullptr, nullptr, 0, nullptr, 0, 640, (long)640 * 640, 640, 640);

  // 8) fusion 1: U1 = z*Uw + (1-z)*Us, z = sigmoid([Uw|Us]@F1 + b1)
  gemm_bt<2><<<dim3(40, 64, 1), b256, 0, stream>>>(
      Uw, 5120, Us, 5120, WtF, 10240, 10240,
      U1, 5120, F1_b, Uw, Us, 5120, nullptr, 0, 0, 0, 0, 0);

  // 9) convert F2 into the (now free) WtF buffer, then fusion 2 -> U2
  conv_transpose<<<dim3(160, 320), b256, 0, stream>>>(F2_w, 10240, 5120, WtF, 10240);
  gemm_bt<2><<<dim3(40, 64, 1), b256, 0, stream>>>(
      U1, 5120, US, 5120, WtF, 10240, 10240,
      U2, 5120, F2_b, U1, US, 5120, nullptr, 0, 0, 0, 0, 0);

  // 10) FFN
  gemm_bt<3><<<dim3(16, 64, 1), b256, 0, stream>>>(
      U2, 5120, nullptr, 1 << 30, Wt_l1, 5120, 5120,
      Tb, 2048, l1_b, nullptr, nullptr, 0, nullptr, 0, 0, 0, 0, 0);
  gemm_bt<4><<<dim3(5, 64, 1), b256, 0, stream>>>(
      Tb, 2048, nullptr, 1 << 30, Wt_l2, 2048, 2048,
      outp, 640, l2_b, nullptr, nullptr, 0, Hs, 640, 0, 0, 0, 0);
}

// Round 2
// 4709.135 us; speedup vs baseline: 1.0331x; 1.0331x over previous
//
#include <hip/hip_runtime.h>
#include <cstdint>
#include <cstddef>

typedef __attribute__((ext_vector_type(8))) __bf16 bf16x8;
typedef __attribute__((ext_vector_type(4))) float f32x4;

static constexpr int kNS   = 8192;
static constexpr int kNW   = 65536;
static constexpr int kNSEC = 1024;
static constexpr int kEW   = 131072;
static constexpr int kES   = 262144;
static constexpr int kESEC = 16384;

__device__ __forceinline__ float eluf(float x)  { return x > 0.f ? x : (__expf(x) - 1.f); }
__device__ __forceinline__ float sigmf(float x) { return 1.f / (1.f + __expf(-x)); }

// async global -> LDS, 16 bytes per lane (dest must be linear in lane order)
__device__ __forceinline__ void gload16(const __bf16* g, __bf16* l) {
  __builtin_amdgcn_global_load_lds((const __attribute__((address_space(1))) unsigned int*)g,
                                   (__attribute__((address_space(3))) unsigned int*)l,
                                   16, 0, 0);
}

// ---------------------------------------------------------------------------
// Weight convert + transpose: W[K][N] f32 -> Wt[N][KP] bf16 (zero-pad k>=K)
// ---------------------------------------------------------------------------
__global__ __launch_bounds__(256) void conv_transpose(const float* __restrict__ W, int K, int N,
                                                      __bf16* __restrict__ Wt, int KP) {
  __shared__ float t[32][33];
  const int nb = blockIdx.x * 32, kb = blockIdx.y * 32;
  const int tx = threadIdx.x & 31, ty = threadIdx.x >> 5;
#pragma unroll
  for (int i = ty; i < 32; i += 8) {
    const int k = kb + i;
    t[i][tx] = (k < K) ? W[(long)k * N + nb + tx] : 0.f;
  }
  __syncthreads();
#pragma unroll
  for (int i = ty; i < 32; i += 8) {
    Wt[(long)(nb + i) * KP + kb + tx] = (__bf16)t[tx][i];
  }
}

__global__ __launch_bounds__(256) void conv_bf(const float* __restrict__ in, __bf16* __restrict__ outb, long n) {
  long i = (long)blockIdx.x * blockDim.x + threadIdx.x;
  if (i < n) outb[i] = (__bf16)in[i];
}

// ---------------------------------------------------------------------------
// Head vectors: out[h][k] = sum_c W[k][h*640+c] * a[h][c]   (k<Kd, pad->0)
// ---------------------------------------------------------------------------
__global__ __launch_bounds__(256) void head_vecs(const float* __restrict__ W, const float* __restrict__ a,
                                                 float* __restrict__ outv, int Kd, int KP) {
  const int gid = blockIdx.x * blockDim.x + threadIdx.x;
  if (gid >= 8 * KP) return;
  const int h = gid / KP, k = gid - h * KP;
  float s = 0.f;
  if (k < Kd) {
    const float* wr = W + (long)k * 5120 + h * 640;
    const float* ar = a + h * 640;
    for (int c = 0; c < 640; ++c) s += wr[c] * ar[c];
  }
  outv[gid] = s;
}

// ---------------------------------------------------------------------------
// Attention logits: out[n][h] = X[n,:Kd] . vec[h,:Kd]    (1 wave per node)
// ---------------------------------------------------------------------------
__global__ __launch_bounds__(256) void att_logits(const float* __restrict__ X, int ldx, int Kd,
                                                  const float* __restrict__ vec, int KP,
                                                  float* __restrict__ outl, int N) {
  const int lane = threadIdx.x & 63;
  const int node = blockIdx.x * 4 + (threadIdx.x >> 6);
  if (node >= N) return;
  const float* xr = X + (long)node * ldx;
  float p[8];
#pragma unroll
  for (int h = 0; h < 8; ++h) p[h] = 0.f;
  for (int k = lane; k < Kd; k += 64) {
    const float xv = xr[k];
#pragma unroll
    for (int h = 0; h < 8; ++h) p[h] += xv * vec[h * KP + k];
  }
#pragma unroll
  for (int h = 0; h < 8; ++h) {
    float v = p[h];
    for (int o2 = 32; o2; o2 >>= 1) v += __shfl_down(v, o2);
    if (lane == 0) outl[(long)node * 8 + h] = v;
  }
}

// ---------------------------------------------------------------------------
// CSR build
// ---------------------------------------------------------------------------
__global__ __launch_bounds__(256) void edge_count(const int* __restrict__ dst, int E, int* __restrict__ cnt) {
  const int gid = blockIdx.x * blockDim.x + threadIdx.x;
  if (gid < E) atomicAdd(&cnt[dst[gid]], 1);
}

__global__ __launch_bounds__(1024) void scan_off(const int* __restrict__ cnt, int* __restrict__ offo) {
  __shared__ int part[1024];
  const int tid = threadIdx.x;
  const int base = tid * 8;
  int loc[8];
  int s = 0;
#pragma unroll
  for (int i = 0; i < 8; ++i) { loc[i] = s; s += cnt[base + i]; }
  part[tid] = s;
  __syncthreads();
  for (int d2 = 1; d2 < 1024; d2 <<= 1) {
    int v = (tid >= d2) ? part[tid - d2] : 0;
    __syncthreads();
    part[tid] += v;
    __syncthreads();
  }
  const int pre = (tid > 0) ? part[tid - 1] : 0;
#pragma unroll
  for (int i = 0; i < 8; ++i) offo[base + i] = pre + loc[i];
  if (tid == 1023) offo[8192] = part[1023];
}

__global__ __launch_bounds__(256) void edge_fill(const int* __restrict__ src, const int* __restrict__ dst, int E,
                                                 const int* __restrict__ offo, int* __restrict__ cur,
                                                 int* __restrict__ ssrc) {
  const int gid = blockIdx.x * blockDim.x + threadIdx.x;
  if (gid < E) {
    const int d = dst[gid];
    const int p = offo[d] + atomicAdd(&cur[d], 1);
    ssrc[p] = src[gid];
  }
}

// ---------------------------------------------------------------------------
// GAT aggregation (one block per dst sentence)
// ---------------------------------------------------------------------------
template <int FPAD, int F, bool XPH, bool BIASELU>
__global__ __launch_bounds__(256) void gat_agg(const int* __restrict__ seg_off, const int* __restrict__ ssrc,
                                               const float* __restrict__ als, const float* __restrict__ ald,
                                               const float* __restrict__ X, int ldx,
                                               __bf16* __restrict__ outp, int ldo,
                                               const float* __restrict__ bias) {
  constexpr int L = (FPAD * 8) / 256;
  const int d = blockIdx.x;
  const int tid = threadIdx.x;
  const int o0 = seg_off[d], o1 = seg_off[d + 1];
  const int deg = o1 - o0;
  __shared__ float exl[64][8];
  __shared__ int ssl[64];
  __shared__ float aldd[8];
  __shared__ float den_s[8];
  if (tid < 8) { aldd[tid] = ald[(long)d * 8 + tid]; den_s[tid] = 0.f; }
  float acc[L];
  int hh[L], xc[L];
  bool vld[L];
#pragma unroll
  for (int l = 0; l < L; ++l) {
    acc[l] = 0.f;
    const int idx = tid + l * 256;
    const int h = idx / FPAD, f = idx - h * FPAD;
    hh[l] = h;
    vld[l] = (f < F);
    xc[l] = XPH ? idx : f;
  }
  __syncthreads();
  for (int base = 0; base < deg; base += 64) {
    const int nc = min(64, deg - base);
    if (tid < nc) ssl[tid] = ssrc[o0 + base + tid];
    __syncthreads();
    for (int t = tid; t < nc * 8; t += 256) {
      const int e = t >> 3, h = t & 7;
      float v = als[(long)ssl[e] * 8 + h] + aldd[h];
      v = v > 0.f ? v : 0.2f * v;
      exl[e][h] = __expf(v);
    }
    __syncthreads();
    if (tid < 8) {
      float s = 0.f;
      for (int e = 0; e < nc; ++e) s += exl[e][tid];
      den_s[tid] += s;
    }
    for (int e = 0; e < nc; ++e) {
      const float* xr = X + (long)ssl[e] * ldx;
      const float* ex8 = exl[e];
#pragma unroll
      for (int l = 0; l < L; ++l)
        if (vld[l]) acc[l] += ex8[hh[l]] * xr[xc[l]];
    }
    __syncthreads();
  }
#pragma unroll
  for (int l = 0; l < L; ++l) {
    const int idx = tid + l * 256;
    float r = acc[l] / (den_s[hh[l]] + 1e-16f);
    if constexpr (BIASELU) { r += bias[idx]; r = eluf(r); }
    outp[(long)d * ldo + idx] = (__bf16)r;
  }
}

// ---------------------------------------------------------------------------
// bf16 MFMA GEMM, C[M,N] = A[M,K] * Bt[N,K]^T  (both row-major bf16)
// 128x128 tile, BK=32, 4 waves, double-buffered LDS staged via
// global_load_lds width=16 (m97 structure). LDS 16B-slot XOR swizzle:
// logical (row, slot c) stored at physical slot c ^ ((row>>1)&3) -> the 16
// fr-lanes of a frag read cover all 8 bank positions (2-way = free).
// Swizzle is applied on BOTH sides: pre-swizzled global source column in
// stage(), swizzled ds_read offset in the frag loads (LDS dest stays linear).
// EPI: 0 store f32 | 1 bias+ELU->bf16 | 2 sigmoid-gate mix->bf16
//      3 bias->bf16 | 4 bias+residual->f32
// ---------------------------------------------------------------------------
template <int EPI>
__global__ __launch_bounds__(256) void gemm_bt(
    const __bf16* __restrict__ A, int lda, const __bf16* __restrict__ A2, int ksplit,
    const __bf16* __restrict__ Bt, int ldb, int K,
    void* __restrict__ Cout, int ldc,
    const float* __restrict__ bias,
    const __bf16* __restrict__ Xg, const __bf16* __restrict__ Yg, int ldxy,
    const float* __restrict__ Res, int ldres,
    long a_zs, long bt_zs, long c_zs, int b_zs) {
  __shared__ __bf16 sA[2][128 * 32];
  __shared__ __bf16 sB[2][128 * 32];
  const int tid = threadIdx.x;
  const int z = blockIdx.z;
  const int m0 = blockIdx.y * 128, n0 = blockIdx.x * 128;
  const __bf16* Ab = A + (long)z * a_zs;
  const __bf16* A2b = A2 ? A2 + (long)z * a_zs : nullptr;
  const __bf16* Btb = Bt + (long)z * bt_zs;
  const int lane = tid & 63;
  const int wv = tid >> 6, wr = wv >> 1, wc = wv & 1;
  const int fr = lane & 15, fq = lane >> 4;

  // staging: thread tid owns physical 16B slot (tid&3) of row (tid>>2) (and +64)
  const int r0 = tid >> 2, r1 = r0 + 64;
  const int csw = (((tid & 3) ^ ((r0 >> 1) & 3)) * 8);  // swizzled source column (elems)
  const int ldst0 = tid * 8;                            // linear LDS dest (elems)
  const int ldst1 = 2048 + tid * 8;

  f32x4 acc[4][4];
#pragma unroll
  for (int i = 0; i < 4; ++i)
#pragma unroll
    for (int j = 0; j < 4; ++j)
#pragma unroll
      for (int r = 0; r < 4; ++r) acc[i][j][r] = 0.f;

  // frag read offsets (swizzled slot): logical slot fq of row -> phys fq^((row>>1)&3)
  const int fsw = (fq ^ ((fr >> 1) & 3)) * 8;
  int aof[4], bof[4];
#pragma unroll
  for (int i = 0; i < 4; ++i) {
    aof[i] = (wr * 64 + i * 16 + fr) * 32 + fsw;
    bof[i] = (wc * 64 + i * 16 + fr) * 32 + fsw;
  }

  const int nkt = K >> 5;
  auto stage = [&](int buf, int kt) {
    const int k0 = kt * 32;
    const __bf16* As = Ab;
    int kr = k0;
    if (A2b && k0 >= ksplit) { As = A2b; kr = k0 - ksplit; }
    gload16(As + (long)(m0 + r0) * lda + kr + csw, &sA[buf][ldst0]);
    gload16(As + (long)(m0 + r1) * lda + kr + csw, &sA[buf][ldst1]);
    gload16(Btb + (long)(n0 + r0) * ldb + k0 + csw, &sB[buf][ldst0]);
    gload16(Btb + (long)(n0 + r1) * ldb + k0 + csw, &sB[buf][ldst1]);
  };

  stage(0, 0);
  for (int kt = 0; kt < nkt; ++kt) {
    const int cur = kt & 1;
    __syncthreads();  // drains vmcnt: buf cur is ready; prior reads of cur^1 done
    if (kt + 1 < nkt) stage(cur ^ 1, kt + 1);
    bf16x8 af[4], bfv[4];
#pragma unroll
    for (int i = 0; i < 4; ++i) {
      af[i] = *(const bf16x8*)(&sA[cur][aof[i]]);
      bfv[i] = *(const bf16x8*)(&sB[cur][bof[i]]);
    }
#pragma unroll
    for (int i = 0; i < 4; ++i)
#pragma unroll
      for (int j = 0; j < 4; ++j)
        acc[i][j] = __builtin_amdgcn_mfma_f32_16x16x32_bf16(af[i], bfv[j], acc[i][j], 0, 0, 0);
  }

  const float* biasb = bias ? bias + (long)z * b_zs : nullptr;
#pragma unroll
  for (int i = 0; i < 4; ++i) {
#pragma unroll
    for (int j = 0; j < 4; ++j) {
#pragma unroll
      for (int r = 0; r < 4; ++r) {
        const int mm = m0 + wr * 64 + i * 16 + fq * 4 + r;
        const int nn = n0 + wc * 64 + j * 16 + fr;
        const float v = acc[i][j][r];
        const long cidx = (long)mm * ldc + nn + (long)z * c_zs;
        if constexpr (EPI == 0) {
          ((float*)Cout)[cidx] = v;
        } else if constexpr (EPI == 1) {
          ((__bf16*)Cout)[cidx] = (__bf16)eluf(v + biasb[nn]);
        } else if constexpr (EPI == 2) {
          const float zt = sigmf(v + biasb[nn]);
          const float x = (float)Xg[(long)mm * ldxy + nn];
          const float y = (float)Yg[(long)mm * ldxy + nn];
          ((__bf16*)Cout)[cidx] = (__bf16)(zt * x + (1.f - zt) * y);
        } else if constexpr (EPI == 3) {
          ((__bf16*)Cout)[cidx] = (__bf16)(v + biasb[nn]);
        } else {
          ((float*)Cout)[cidx] = v + biasb[nn] + Res[(long)mm * ldres + nn];
        }
      }
    }
  }
}

// ---------------------------------------------------------------------------
extern "C" void kernel_launch(void* const* d_in, const int* in_sizes, int n_in,
                              void* d_out, int out_size, void* d_ws, size_t ws_size,
                              hipStream_t stream) {
  (void)in_sizes; (void)n_in; (void)out_size; (void)ws_size;
  const float* Hs    = (const float*)d_in[0];
  const float* Hw    = (const float*)d_in[1];
  const float* HSec  = (const float*)d_in[2];
  const int* w2s     = (const int*)d_in[3];
  const int* s2s     = (const int*)d_in[4];
  const int* S2s     = (const int*)d_in[5];
  const float* Ww_src = (const float*)d_in[6];
  const float* Ww_dst = (const float*)d_in[7];
  const float* aw_src = (const float*)d_in[8];
  const float* aw_dst = (const float*)d_in[9];
  const float* bw     = (const float*)d_in[10];
  const float* Wss    = (const float*)d_in[11];
  const float* as_src = (const float*)d_in[12];
  const float* as_dst = (const float*)d_in[13];
  const float* bs     = (const float*)d_in[14];
  const float* WS_src = (const float*)d_in[15];
  const float* WS_dst = (const float*)d_in[16];
  const float* aS_src = (const float*)d_in[17];
  const float* aS_dst = (const float*)d_in[18];
  const float* bS     = (const float*)d_in[19];
  const float* F1_w   = (const float*)d_in[20];
  const float* F1_b   = (const float*)d_in[21];
  const float* F2_w   = (const float*)d_in[22];
  const float* F2_b   = (const float*)d_in[23];
  const float* l1_w   = (const float*)d_in[24];
  const float* l1_b   = (const float*)d_in[25];
  const float* l2_w   = (const float*)d_in[26];
  const float* l2_b   = (const float*)d_in[27];
  float* outp = (float*)d_out;

  char* ws = (char*)d_ws;
  size_t cur_off = 0;
  auto alloc = [&](size_t bytes) -> char* {
    char* p = ws + cur_off;
    cur_off = (cur_off + bytes + 255) & ~(size_t)255;
    return p;
  };

  __bf16* Wt_w  = (__bf16*)alloc((size_t)5120 * 320 * 2);
  __bf16* Wt_s  = (__bf16*)alloc((size_t)5120 * 640 * 2);
  __bf16* Wt_S  = (__bf16*)alloc((size_t)5120 * 512 * 2);
  __bf16* WtF   = (__bf16*)alloc((size_t)5120 * 10240 * 2);  // F1, then reused for F2
  __bf16* Wt_l1 = (__bf16*)alloc((size_t)2048 * 5120 * 2);
  __bf16* Wt_l2 = (__bf16*)alloc((size_t)640 * 2048 * 2);
  __bf16* HS_bf = (__bf16*)alloc((size_t)1024 * 512 * 2);
  float* v_w = (float*)alloc(8 * 320 * 4);
  float* u_w = (float*)alloc(8 * 640 * 4);
  float* v_s = (float*)alloc(8 * 640 * 4);
  float* u_s = (float*)alloc(8 * 640 * 4);
  float* v_S = (float*)alloc(8 * 512 * 4);
  float* u_S = (float*)alloc(8 * 640 * 4);
  float* alw_s = (float*)alloc((size_t)kNW * 8 * 4);
  float* alw_d = (float*)alloc((size_t)kNS * 8 * 4);
  float* als_s = (float*)alloc((size_t)kNS * 8 * 4);
  float* als_d = (float*)alloc((size_t)kNS * 8 * 4);
  float* alS_s = (float*)alloc((size_t)kNSEC * 8 * 4);
  float* alS_d = (float*)alloc((size_t)kNS * 8 * 4);
  int* csr_i  = (int*)alloc((size_t)6 * kNS * 4);
  int* cnt_w = csr_i, *cnt_s = csr_i + kNS, *cnt_S = csr_i + 2 * kNS;
  int* cur_w = csr_i + 3 * kNS, *cur_s = csr_i + 4 * kNS, *cur_S = csr_i + 5 * kNS;
  int* off_w = (int*)alloc((size_t)(kNS + 1) * 4);
  int* off_s = (int*)alloc((size_t)(kNS + 1) * 4);
  int* off_S = (int*)alloc((size_t)(kNS + 1) * 4);
  int* ssrc_w = (int*)alloc((size_t)kEW * 4);
  int* ssrc_s = (int*)alloc((size_t)kES * 4);
  int* ssrc_S = (int*)alloc((size_t)kESEC * 4);
  float* hs_S = (float*)alloc((size_t)1024 * 5120 * 4);
  char* aggreg = alloc((size_t)kNS * 2560 * 2 + (size_t)kNS * 5120 * 2);
  __bf16* agg_w = (__bf16*)aggreg;
  __bf16* agg_s = (__bf16*)(aggreg + (size_t)kNS * 2560 * 2);
  __bf16* U1 = (__bf16*)aggreg;  // alias (agg dead by fusion1)
  __bf16* Uw = (__bf16*)alloc((size_t)kNS * 5120 * 2);
  __bf16* Us = (__bf16*)alloc((size_t)kNS * 5120 * 2);
  __bf16* US = (__bf16*)alloc((size_t)kNS * 5120 * 2);
  __bf16* U2 = Uw;  // alias (Uw dead after fusion1)
  __bf16* Tb = Us;  // alias (Us dead after fusion1)

  const dim3 b256(256);

  // 1) weight conversions/transposes
  conv_transpose<<<dim3(160, 10), b256, 0, stream>>>(Ww_src, 300, 5120, Wt_w, 320);
  conv_transpose<<<dim3(160, 20), b256, 0, stream>>>(Wss, 640, 5120, Wt_s, 640);
  conv_transpose<<<dim3(160, 16), b256, 0, stream>>>(WS_src, 512, 5120, Wt_S, 512);
  conv_transpose<<<dim3(160, 320), b256, 0, stream>>>(F1_w, 10240, 5120, WtF, 10240);
  conv_transpose<<<dim3(64, 160), b256, 0, stream>>>(l1_w, 5120, 2048, Wt_l1, 5120);
  conv_transpose<<<dim3(20, 64), b256, 0, stream>>>(l2_w, 2048, 640, Wt_l2, 2048);
  conv_bf<<<(1024 * 512 + 255) / 256, b256, 0, stream>>>(HSec, HS_bf, (long)1024 * 512);

  // 2) per-head attention vectors
  head_vecs<<<(8 * 320 + 255) / 256, b256, 0, stream>>>(Ww_src, aw_src, v_w, 300, 320);
  head_vecs<<<(8 * 640 + 255) / 256, b256, 0, stream>>>(Ww_dst, aw_dst, u_w, 640, 640);
  head_vecs<<<(8 * 640 + 255) / 256, b256, 0, stream>>>(Wss, as_src, v_s, 640, 640);
  head_vecs<<<(8 * 640 + 255) / 256, b256, 0, stream>>>(Wss, as_dst, u_s, 640, 640);
  head_vecs<<<(8 * 512 + 255) / 256, b256, 0, stream>>>(WS_src, aS_src, v_S, 512, 512);
  head_vecs<<<(8 * 640 + 255) / 256, b256, 0, stream>>>(WS_dst, aS_dst, u_S, 640, 640);

  // 3) attention logits
  att_logits<<<(kNW + 3) / 4, b256, 0, stream>>>(Hw, 300, 300, v_w, 320, alw_s, kNW);
  att_logits<<<(kNS + 3) / 4, b256, 0, stream>>>(Hs, 640, 640, u_w, 640, alw_d, kNS);
  att_logits<<<(kNS + 3) / 4, b256, 0, stream>>>(Hs, 640, 640, v_s, 640, als_s, kNS);
  att_logits<<<(kNS + 3) / 4, b256, 0, stream>>>(Hs, 640, 640, u_s, 640, als_d, kNS);
  att_logits<<<(kNSEC + 3) / 4, b256, 0, stream>>>(HSec, 512, 512, v_S, 512, alS_s, kNSEC);
  att_logits<<<(kNS + 3) / 4, b256, 0, stream>>>(Hs, 640, 640, u_S, 640, alS_d, kNS);

  // 4) CSR build (per layer)
  hipMemsetAsync(csr_i, 0, (size_t)6 * kNS * 4, stream);
  edge_count<<<(kEW + 255) / 256, b256, 0, stream>>>(w2s + kEW, kEW, cnt_w);
  edge_count<<<(kES + 255) / 256, b256, 0, stream>>>(s2s + kES, kES, cnt_s);
  edge_count<<<(kESEC + 255) / 256, b256, 0, stream>>>(S2s + kESEC, kESEC, cnt_S);
  scan_off<<<1, 1024, 0, stream>>>(cnt_w, off_w);
  scan_off<<<1, 1024, 0, stream>>>(cnt_s, off_s);
  scan_off<<<1, 1024, 0, stream>>>(cnt_S, off_S);
  edge_fill<<<(kEW + 255) / 256, b256, 0, stream>>>(w2s, w2s + kEW, kEW, off_w, cur_w, ssrc_w);
  edge_fill<<<(kES + 255) / 256, b256, 0, stream>>>(s2s, s2s + kES, kES, off_s, cur_s, ssrc_s);
  edge_fill<<<(kESEC + 255) / 256, b256, 0, stream>>>(S2s, S2s + kESEC, kESEC, off_S, cur_S, ssrc_S);

  // 5) section source transform: hs_S = HS @ WS_src  (f32 out)
  gemm_bt<0><<<dim3(40, 8, 1), b256, 0, stream>>>(
      HS_bf, 512, nullptr, 1 << 30, Wt_S, 512, 512,
      hs_S, 5120, nullptr, nullptr, nullptr, 0, nullptr, 0, 0, 0, 0, 0);

  // 6) aggregations
  gat_agg<320, 300, false, false><<<kNS, b256, 0, stream>>>(off_w, ssrc_w, alw_s, alw_d, Hw, 300, agg_w, 2560, nullptr);
  gat_agg<640, 640, false, false><<<kNS, b256, 0, stream>>>(off_s, ssrc_s, als_s, als_d, Hs, 640, agg_s, 5120, nullptr);
  gat_agg<640, 640, true, true><<<kNS, b256, 0, stream>>>(off_S, ssrc_S, alS_s, alS_d, hs_S, 5120, US, 5120, bS);

  // 7) per-head GAT output GEMMs (+bias +ELU)
  gemm_bt<1><<<dim3(5, 64, 8), b256, 0, stream>>>(
      agg_w, 2560, nullptr, 1 << 30, Wt_w, 320, 320,
      Uw, 5120, bw, nullptr, nullptr, 0, nullptr, 0, 320, (long)640 * 320, 640, 640);
  gemm_bt<1><<<dim3(5, 64, 8), b256, 0, stream>>>(
      agg_s, 5120, nullptr, 1 << 30, Wt_s, 640, 640,
      Us, 5120, bs, nullptr, nullptr, 0, nullptr, 0, 640, (long)640 * 640, 640, 640);

  // 8) fusion 1: U1 = z*Uw + (1-z)*Us, z = sigmoid([Uw|Us]@F1 + b1)
  gemm_bt<2><<<dim3(40, 64, 1), b256, 0, stream>>>(
      Uw, 5120, Us, 5120, WtF, 10240, 10240,
      U1, 5120, F1_b, Uw, Us, 5120, nullptr, 0, 0, 0, 0, 0);

  // 9) convert F2 into the (now free) WtF buffer, then fusion 2 -> U2
  conv_transpose<<<dim3(160, 320), b256, 0, stream>>>(F2_w, 10240, 5120, WtF, 10240);
  gemm_bt<2><<<dim3(40, 64, 1), b256, 0, stream>>>(
      U1, 5120, US, 5120, WtF, 10240, 10240,
      U2, 5120, F2_b, U1, US, 5120, nullptr, 0, 0, 0, 0, 0);

  // 10) FFN
  gemm_bt<3><<<dim3(16, 64, 1), b256, 0, stream>>>(
      U2, 5120, nullptr, 1 << 30, Wt_l1, 5120, 5120,
      Tb, 2048, l1_b, nullptr, nullptr, 0, nullptr, 0, 0, 0, 0, 0);
  gemm_bt<4><<<dim3(5, 64, 1), b256, 0, stream>>>(
      Tb, 2048, nullptr, 1 << 30, Wt_l2, 2048, 2048,
      outp, 640, l2_b, nullptr, nullptr, 0, Hs, 640, 0, 0, 0, 0);
}

// Round 3
// 4116.883 us; speedup vs baseline: 1.1818x; 1.1439x over previous
//
#include <hip/hip_runtime.h>
#include <cstdint>
#include <cstddef>

typedef __attribute__((ext_vector_type(8))) __bf16 bf16x8;
typedef __attribute__((ext_vector_type(4))) float f32x4;

static constexpr int kNS   = 8192;
static constexpr int kNW   = 65536;
static constexpr int kNSEC = 1024;
static constexpr int kEW   = 131072;
static constexpr int kES   = 262144;
static constexpr int kESEC = 16384;

__device__ __forceinline__ float eluf(float x)  { return x > 0.f ? x : (__expf(x) - 1.f); }
__device__ __forceinline__ float sigmf(float x) { return 1.f / (1.f + __expf(-x)); }

// async global -> LDS, 16 bytes per lane (dest must be linear in lane order)
__device__ __forceinline__ void gload16(const __bf16* g, __bf16* l) {
  __builtin_amdgcn_global_load_lds((const __attribute__((address_space(1))) unsigned int*)g,
                                   (__attribute__((address_space(3))) unsigned int*)l,
                                   16, 0, 0);
}

// ---------------------------------------------------------------------------
// Weight convert + transpose: W[K][N] f32 -> Wt[N][KP] bf16 (zero-pad k>=K)
// ---------------------------------------------------------------------------
__global__ __launch_bounds__(256) void conv_transpose(const float* __restrict__ W, int K, int N,
                                                      __bf16* __restrict__ Wt, int KP) {
  __shared__ float t[32][33];
  const int nb = blockIdx.x * 32, kb = blockIdx.y * 32;
  const int tx = threadIdx.x & 31, ty = threadIdx.x >> 5;
#pragma unroll
  for (int i = ty; i < 32; i += 8) {
    const int k = kb + i;
    t[i][tx] = (k < K) ? W[(long)k * N + nb + tx] : 0.f;
  }
  __syncthreads();
#pragma unroll
  for (int i = ty; i < 32; i += 8) {
    Wt[(long)(nb + i) * KP + kb + tx] = (__bf16)t[tx][i];
  }
}

__global__ __launch_bounds__(256) void conv_bf(const float* __restrict__ in, __bf16* __restrict__ outb, long n) {
  long i = (long)blockIdx.x * blockDim.x + threadIdx.x;
  if (i < n) outb[i] = (__bf16)in[i];
}

// ---------------------------------------------------------------------------
// Head vectors: out[h][k] = sum_c W[k][h*640+c] * a[h][c]   (k<Kd, pad->0)
// ---------------------------------------------------------------------------
__global__ __launch_bounds__(256) void head_vecs(const float* __restrict__ W, const float* __restrict__ a,
                                                 float* __restrict__ outv, int Kd, int KP) {
  const int gid = blockIdx.x * blockDim.x + threadIdx.x;
  if (gid >= 8 * KP) return;
  const int h = gid / KP, k = gid - h * KP;
  float s = 0.f;
  if (k < Kd) {
    const float* wr = W + (long)k * 5120 + h * 640;
    const float* ar = a + h * 640;
    for (int c = 0; c < 640; ++c) s += wr[c] * ar[c];
  }
  outv[gid] = s;
}

// ---------------------------------------------------------------------------
// Attention logits: out[n][h] = X[n,:Kd] . vec[h,:Kd]    (1 wave per node)
// ---------------------------------------------------------------------------
__global__ __launch_bounds__(256) void att_logits(const float* __restrict__ X, int ldx, int Kd,
                                                  const float* __restrict__ vec, int KP,
                                                  float* __restrict__ outl, int N) {
  const int lane = threadIdx.x & 63;
  const int node = blockIdx.x * 4 + (threadIdx.x >> 6);
  if (node >= N) return;
  const float* xr = X + (long)node * ldx;
  float p[8];
#pragma unroll
  for (int h = 0; h < 8; ++h) p[h] = 0.f;
  for (int k = lane; k < Kd; k += 64) {
    const float xv = xr[k];
#pragma unroll
    for (int h = 0; h < 8; ++h) p[h] += xv * vec[h * KP + k];
  }
#pragma unroll
  for (int h = 0; h < 8; ++h) {
    float v = p[h];
    for (int o2 = 32; o2; o2 >>= 1) v += __shfl_down(v, o2);
    if (lane == 0) outl[(long)node * 8 + h] = v;
  }
}

// ---------------------------------------------------------------------------
// CSR build
// ---------------------------------------------------------------------------
__global__ __launch_bounds__(256) void edge_count(const int* __restrict__ dst, int E, int* __restrict__ cnt) {
  const int gid = blockIdx.x * blockDim.x + threadIdx.x;
  if (gid < E) atomicAdd(&cnt[dst[gid]], 1);
}

__global__ __launch_bounds__(1024) void scan_off(const int* __restrict__ cnt, int* __restrict__ offo) {
  __shared__ int part[1024];
  const int tid = threadIdx.x;
  const int base = tid * 8;
  int loc[8];
  int s = 0;
#pragma unroll
  for (int i = 0; i < 8; ++i) { loc[i] = s; s += cnt[base + i]; }
  part[tid] = s;
  __syncthreads();
  for (int d2 = 1; d2 < 1024; d2 <<= 1) {
    int v = (tid >= d2) ? part[tid - d2] : 0;
    __syncthreads();
    part[tid] += v;
    __syncthreads();
  }
  const int pre = (tid > 0) ? part[tid - 1] : 0;
#pragma unroll
  for (int i = 0; i < 8; ++i) offo[base + i] = pre + loc[i];
  if (tid == 1023) offo[8192] = part[1023];
}

__global__ __launch_bounds__(256) void edge_fill(const int* __restrict__ src, const int* __restrict__ dst, int E,
                                                 const int* __restrict__ offo, int* __restrict__ cur,
                                                 int* __restrict__ ssrc) {
  const int gid = blockIdx.x * blockDim.x + threadIdx.x;
  if (gid < E) {
    const int d = dst[gid];
    const int p = offo[d] + atomicAdd(&cur[d], 1);
    ssrc[p] = src[gid];
  }
}

// ---------------------------------------------------------------------------
// GAT aggregation (one block per dst sentence)
// ---------------------------------------------------------------------------
template <int FPAD, int F, bool XPH, bool BIASELU>
__global__ __launch_bounds__(256) void gat_agg(const int* __restrict__ seg_off, const int* __restrict__ ssrc,
                                               const float* __restrict__ als, const float* __restrict__ ald,
                                               const float* __restrict__ X, int ldx,
                                               __bf16* __restrict__ outp, int ldo,
                                               const float* __restrict__ bias) {
  constexpr int L = (FPAD * 8) / 256;
  const int d = blockIdx.x;
  const int tid = threadIdx.x;
  const int o0 = seg_off[d], o1 = seg_off[d + 1];
  const int deg = o1 - o0;
  __shared__ float exl[64][8];
  __shared__ int ssl[64];
  __shared__ float aldd[8];
  __shared__ float den_s[8];
  if (tid < 8) { aldd[tid] = ald[(long)d * 8 + tid]; den_s[tid] = 0.f; }
  float acc[L];
  int hh[L], xc[L];
  bool vld[L];
#pragma unroll
  for (int l = 0; l < L; ++l) {
    acc[l] = 0.f;
    const int idx = tid + l * 256;
    const int h = idx / FPAD, f = idx - h * FPAD;
    hh[l] = h;
    vld[l] = (f < F);
    xc[l] = XPH ? idx : f;
  }
  __syncthreads();
  for (int base = 0; base < deg; base += 64) {
    const int nc = min(64, deg - base);
    if (tid < nc) ssl[tid] = ssrc[o0 + base + tid];
    __syncthreads();
    for (int t = tid; t < nc * 8; t += 256) {
      const int e = t >> 3, h = t & 7;
      float v = als[(long)ssl[e] * 8 + h] + aldd[h];
      v = v > 0.f ? v : 0.2f * v;
      exl[e][h] = __expf(v);
    }
    __syncthreads();
    if (tid < 8) {
      float s = 0.f;
      for (int e = 0; e < nc; ++e) s += exl[e][tid];
      den_s[tid] += s;
    }
    for (int e = 0; e < nc; ++e) {
      const float* xr = X + (long)ssl[e] * ldx;
      const float* ex8 = exl[e];
#pragma unroll
      for (int l = 0; l < L; ++l)
        if (vld[l]) acc[l] += ex8[hh[l]] * xr[xc[l]];
    }
    __syncthreads();
  }
#pragma unroll
  for (int l = 0; l < L; ++l) {
    const int idx = tid + l * 256;
    float r = acc[l] / (den_s[hh[l]] + 1e-16f);
    if constexpr (BIASELU) { r += bias[idx]; r = eluf(r); }
    outp[(long)d * ldo + idx] = (__bf16)r;
  }
}

// ---------------------------------------------------------------------------
// 128x128-tile MFMA GEMM (m97-class, 2-barrier) -- used for small/batched GEMMs.
// ---------------------------------------------------------------------------
template <int EPI>
__global__ __launch_bounds__(256) void gemm_bt(
    const __bf16* __restrict__ A, int lda, const __bf16* __restrict__ A2, int ksplit,
    const __bf16* __restrict__ Bt, int ldb, int K,
    void* __restrict__ Cout, int ldc,
    const float* __restrict__ bias,
    const __bf16* __restrict__ Xg, const __bf16* __restrict__ Yg, int ldxy,
    const float* __restrict__ Res, int ldres,
    long a_zs, long bt_zs, long c_zs, int b_zs) {
  __shared__ __bf16 sA[2][128 * 32];
  __shared__ __bf16 sB[2][128 * 32];
  const int tid = threadIdx.x;
  const int z = blockIdx.z;
  const int m0 = blockIdx.y * 128, n0 = blockIdx.x * 128;
  const __bf16* Ab = A + (long)z * a_zs;
  const __bf16* A2b = A2 ? A2 + (long)z * a_zs : nullptr;
  const __bf16* Btb = Bt + (long)z * bt_zs;
  const int lane = tid & 63;
  const int wv = tid >> 6, wr = wv >> 1, wc = wv & 1;
  const int fr = lane & 15, fq = lane >> 4;

  const int r0 = tid >> 2, r1 = r0 + 64;
  const int csw = (((tid & 3) ^ ((r0 >> 1) & 3)) * 8);
  const int ldst0 = tid * 8;
  const int ldst1 = 2048 + tid * 8;

  f32x4 acc[4][4];
#pragma unroll
  for (int i = 0; i < 4; ++i)
#pragma unroll
    for (int j = 0; j < 4; ++j)
#pragma unroll
      for (int r = 0; r < 4; ++r) acc[i][j][r] = 0.f;

  const int fsw = (fq ^ ((fr >> 1) & 3)) * 8;
  int aof[4], bof[4];
#pragma unroll
  for (int i = 0; i < 4; ++i) {
    aof[i] = (wr * 64 + i * 16 + fr) * 32 + fsw;
    bof[i] = (wc * 64 + i * 16 + fr) * 32 + fsw;
  }

  const int nkt = K >> 5;
  auto stage = [&](int buf, int kt) {
    const int k0 = kt * 32;
    const __bf16* As = Ab;
    int kr = k0;
    if (A2b && k0 >= ksplit) { As = A2b; kr = k0 - ksplit; }
    gload16(As + (long)(m0 + r0) * lda + kr + csw, &sA[buf][ldst0]);
    gload16(As + (long)(m0 + r1) * lda + kr + csw, &sA[buf][ldst1]);
    gload16(Btb + (long)(n0 + r0) * ldb + k0 + csw, &sB[buf][ldst0]);
    gload16(Btb + (long)(n0 + r1) * ldb + k0 + csw, &sB[buf][ldst1]);
  };

  stage(0, 0);
  for (int kt = 0; kt < nkt; ++kt) {
    const int cur = kt & 1;
    __syncthreads();
    if (kt + 1 < nkt) stage(cur ^ 1, kt + 1);
    bf16x8 af[4], bfv[4];
#pragma unroll
    for (int i = 0; i < 4; ++i) {
      af[i] = *(const bf16x8*)(&sA[cur][aof[i]]);
      bfv[i] = *(const bf16x8*)(&sB[cur][bof[i]]);
    }
#pragma unroll
    for (int i = 0; i < 4; ++i)
#pragma unroll
      for (int j = 0; j < 4; ++j)
        acc[i][j] = __builtin_amdgcn_mfma_f32_16x16x32_bf16(af[i], bfv[j], acc[i][j], 0, 0, 0);
  }

  const float* biasb = bias ? bias + (long)z * b_zs : nullptr;
#pragma unroll
  for (int i = 0; i < 4; ++i) {
#pragma unroll
    for (int j = 0; j < 4; ++j) {
#pragma unroll
      for (int r = 0; r < 4; ++r) {
        const int mm = m0 + wr * 64 + i * 16 + fq * 4 + r;
        const int nn = n0 + wc * 64 + j * 16 + fr;
        const float v = acc[i][j][r];
        const long cidx = (long)mm * ldc + nn + (long)z * c_zs;
        if constexpr (EPI == 0) {
          ((float*)Cout)[cidx] = v;
        } else if constexpr (EPI == 1) {
          ((__bf16*)Cout)[cidx] = (__bf16)eluf(v + biasb[nn]);
        } else if constexpr (EPI == 2) {
          const float zt = sigmf(v + biasb[nn]);
          const float x = (float)Xg[(long)mm * ldxy + nn];
          const float y = (float)Yg[(long)mm * ldxy + nn];
          ((__bf16*)Cout)[cidx] = (__bf16)(zt * x + (1.f - zt) * y);
        } else if constexpr (EPI == 3) {
          ((__bf16*)Cout)[cidx] = (__bf16)(v + biasb[nn]);
        } else {
          ((float*)Cout)[cidx] = v + biasb[nn] + Res[(long)mm * ldres + nn];
        }
      }
    }
  }
}

// ---------------------------------------------------------------------------
// 256x256-tile 8-wave deep-pipelined MFMA GEMM (m201-class 8-phase schedule).
// BK=64 split into two 32-wide k-slices; LDS = [2 buf][2 kk][256x32] per
// matrix = 128 KiB. Per K-tile: 4 phases (quadrant = {kk, M-half}), each:
//   {8|4 ds_read_b128} {1 half-slice stage: 2 global_load_lds}
//   s_barrier; lgkmcnt(0); setprio(1); 16 MFMA; setprio(0);
//   [counted vmcnt at ends of q1/q3]; s_barrier
// Per-thread vmcnt ledger (2 loads/stage, 4 stages/tile, staged 1 tile
// ahead): steady-state outstanding at wait = 8, need oldest 4 -> vmcnt(4);
// last tile's q1 -> vmcnt(0) (no prefetch issued). Stage always targets the
// opposite-parity buffer whose last reader was >=4 barriers ago.
// XOR swizzle (slot ^ (row>>1)&3) applied on BOTH sides (pre-swizzled global
// source column, swizzled ds_read offset); LDS dest stays linear (m104 rule).
// EPI: 2 sigmoid-gate mix->bf16 | 3 bias->bf16
// ---------------------------------------------------------------------------
template <int EPI>
__global__ __launch_bounds__(512, 2) void gemm256(
    const __bf16* __restrict__ A, int lda, const __bf16* __restrict__ A2, int ksplit,
    const __bf16* __restrict__ Bt, int ldb, int K,
    void* __restrict__ Cout, int ldc,
    const float* __restrict__ bias,
    const __bf16* __restrict__ Xg, const __bf16* __restrict__ Yg, int ldxy,
    int nn_tiles) {
  __shared__ __bf16 sA[2][2][256 * 32];
  __shared__ __bf16 sB[2][2][256 * 32];
  const int tid = threadIdx.x;

  // bijective XCD swizzle (m204)
  const int nwg = gridDim.x;
  const int lin = blockIdx.x;
  const int qq = nwg >> 3, rr = nwg & 7;
  const int xcd = lin & 7, pos = lin >> 3;
  const int swz = (xcd < rr ? xcd * (qq + 1) : rr * (qq + 1) + (xcd - rr) * qq) + pos;
  const int m0 = (swz / nn_tiles) * 256;
  const int n0 = (swz % nn_tiles) * 256;

  const int lane = tid & 63;
  const int wv = tid >> 6, wm = wv >> 2, wn = wv & 3;
  const int fr = lane & 15, fq = lane >> 4;

  // staging geometry: 512 threads x 16B cover 128 rows x 64B per issue; 2 issues
  const int srow = tid >> 2;   // row within issue (0..127)
  const int pslot = tid & 3;   // physical 16B slot

  auto stageA = [&](int bp, int tt, int kk) {
    const int kcol0 = tt * 64 + kk * 32;
    const __bf16* src = A;
    int kc = kcol0;
    if (A2 && kcol0 >= ksplit) { src = A2; kc = kcol0 - ksplit; }
    __bf16* dst = &sA[bp][kk][0];
#pragma unroll
    for (int i = 0; i < 2; ++i) {
      const int r = i * 128 + srow;
      const int l = pslot ^ ((r >> 1) & 3);
      gload16(src + (long)(m0 + r) * lda + kc + l * 8, dst + (i * 512 + tid) * 8);
    }
  };
  auto stageB = [&](int bp, int tt, int kk) {
    const int kcol0 = tt * 64 + kk * 32;
    __bf16* dst = &sB[bp][kk][0];
#pragma unroll
    for (int i = 0; i < 2; ++i) {
      const int r = i * 128 + srow;
      const int l = pslot ^ ((r >> 1) & 3);
      gload16(Bt + (long)(n0 + r) * ldb + kcol0 + l * 8, dst + (i * 512 + tid) * 8);
    }
  };

  // fragment ds_read offsets (same swizzle formula, full-row form)
  int aoff[8], boff[4];
#pragma unroll
  for (int mf = 0; mf < 8; ++mf) {
    const int ra = wm * 128 + mf * 16 + fr;
    aoff[mf] = ra * 32 + ((fq ^ ((ra >> 1) & 3)) * 8);
  }
#pragma unroll
  for (int nf = 0; nf < 4; ++nf) {
    const int rb = wn * 64 + nf * 16 + fr;
    boff[nf] = rb * 32 + ((fq ^ ((rb >> 1) & 3)) * 8);
  }

  f32x4 acc[8][4];
#pragma unroll
  for (int i = 0; i < 8; ++i)
#pragma unroll
    for (int j = 0; j < 4; ++j)
#pragma unroll
      for (int r = 0; r < 4; ++r) acc[i][j][r] = 0.f;

  const int nkt = K >> 6;

  // prologue: stage tile 0 fully (8 loads/thread); k0 halves ready at vmcnt(4)
  stageA(0, 0, 0); stageB(0, 0, 0); stageA(0, 0, 1); stageB(0, 0, 1);
  asm volatile("s_waitcnt vmcnt(4)" ::: "memory");
  __builtin_amdgcn_s_barrier();

  for (int t = 0; t < nkt; ++t) {
    const int cb = t & 1, nb = cb ^ 1;
    const bool pf = (t + 1 < nkt);
    bf16x8 af[4], bfv[4];

    // ---- q0: kk=0, M-frags 0..3 (reads A_k0 + B_k0)
#pragma unroll
    for (int mf = 0; mf < 4; ++mf) af[mf] = *(const bf16x8*)(&sA[cb][0][aoff[mf]]);
#pragma unroll
    for (int nf = 0; nf < 4; ++nf) bfv[nf] = *(const bf16x8*)(&sB[cb][0][boff[nf]]);
    if (pf) stageA(nb, t + 1, 0);
    __builtin_amdgcn_s_barrier();
    asm volatile("s_waitcnt lgkmcnt(0)" ::: "memory");
    __builtin_amdgcn_sched_barrier(0);
    __builtin_amdgcn_s_setprio(1);
#pragma unroll
    for (int mf = 0; mf < 4; ++mf)
#pragma unroll
      for (int nf = 0; nf < 4; ++nf)
        acc[mf][nf] = __builtin_amdgcn_mfma_f32_16x16x32_bf16(af[mf], bfv[nf], acc[mf][nf], 0, 0, 0);
    __builtin_amdgcn_s_setprio(0);
    __builtin_amdgcn_s_barrier();

    // ---- q1: kk=0, M-frags 4..7 (reuse B_k0 regs)
#pragma unroll
    for (int mf = 0; mf < 4; ++mf) af[mf] = *(const bf16x8*)(&sA[cb][0][aoff[4 + mf]]);
    if (pf) stageB(nb, t + 1, 0);
    __builtin_amdgcn_s_barrier();
    asm volatile("s_waitcnt lgkmcnt(0)" ::: "memory");
    __builtin_amdgcn_sched_barrier(0);
    __builtin_amdgcn_s_setprio(1);
#pragma unroll
    for (int mf = 0; mf < 4; ++mf)
#pragma unroll
      for (int nf = 0; nf < 4; ++nf)
        acc[4 + mf][nf] = __builtin_amdgcn_mfma_f32_16x16x32_bf16(af[mf], bfv[nf], acc[4 + mf][nf], 0, 0, 0);
    __builtin_amdgcn_s_setprio(0);
    // ensure this tile's k1 halves (staged last tile) landed, for ALL waves
    if (pf) asm volatile("s_waitcnt vmcnt(4)" ::: "memory");
    else    asm volatile("s_waitcnt vmcnt(0)" ::: "memory");
    __builtin_amdgcn_s_barrier();

    // ---- q2: kk=1, M-frags 0..3 (reads A_k1 + B_k1)
#pragma unroll
    for (int mf = 0; mf < 4; ++mf) af[mf] = *(const bf16x8*)(&sA[cb][1][aoff[mf]]);
#pragma unroll
    for (int nf = 0; nf < 4; ++nf) bfv[nf] = *(const bf16x8*)(&sB[cb][1][boff[nf]]);
    if (pf) stageA(nb, t + 1, 1);
    __builtin_amdgcn_s_barrier();
    asm volatile("s_waitcnt lgkmcnt(0)" ::: "memory");
    __builtin_amdgcn_sched_barrier(0);
    __builtin_amdgcn_s_setprio(1);
#pragma unroll
    for (int mf = 0; mf < 4; ++mf)
#pragma unroll
      for (int nf = 0; nf < 4; ++nf)
        acc[mf][nf] = __builtin_amdgcn_mfma_f32_16x16x32_bf16(af[mf], bfv[nf], acc[mf][nf], 0, 0, 0);
    __builtin_amdgcn_s_setprio(0);
    __builtin_amdgcn_s_barrier();

    // ---- q3: kk=1, M-frags 4..7
#pragma unroll
    for (int mf = 0; mf < 4; ++mf) af[mf] = *(const bf16x8*)(&sA[cb][1][aoff[4 + mf]]);
    if (pf) stageB(nb, t + 1, 1);
    __builtin_amdgcn_s_barrier();
    asm volatile("s_waitcnt lgkmcnt(0)" ::: "memory");
    __builtin_amdgcn_sched_barrier(0);
    __builtin_amdgcn_s_setprio(1);
#pragma unroll
    for (int mf = 0; mf < 4; ++mf)
#pragma unroll
      for (int nf = 0; nf < 4; ++nf)
        acc[4 + mf][nf] = __builtin_amdgcn_mfma_f32_16x16x32_bf16(af[mf], bfv[nf], acc[4 + mf][nf], 0, 0, 0);
    __builtin_amdgcn_s_setprio(0);
    // next tile's k0 halves (staged this tile at q0/q1) must land before next q0
    if (pf) asm volatile("s_waitcnt vmcnt(4)" ::: "memory");
    __builtin_amdgcn_s_barrier();
  }

  // epilogue
#pragma unroll
  for (int mf = 0; mf < 8; ++mf) {
#pragma unroll
    for (int nf = 0; nf < 4; ++nf) {
#pragma unroll
      for (int r = 0; r < 4; ++r) {
        const int mm = m0 + wm * 128 + mf * 16 + fq * 4 + r;
        const int nn = n0 + wn * 64 + nf * 16 + fr;
        const float v = acc[mf][nf][r];
        const long cidx = (long)mm * ldc + nn;
        if constexpr (EPI == 2) {
          const float zt = sigmf(v + bias[nn]);
          const float x = (float)Xg[(long)mm * ldxy + nn];
          const float y = (float)Yg[(long)mm * ldxy + nn];
          ((__bf16*)Cout)[cidx] = (__bf16)(zt * x + (1.f - zt) * y);
        } else {
          ((__bf16*)Cout)[cidx] = (__bf16)(v + bias[nn]);
        }
      }
    }
  }
}

// ---------------------------------------------------------------------------
extern "C" void kernel_launch(void* const* d_in, const int* in_sizes, int n_in,
                              void* d_out, int out_size, void* d_ws, size_t ws_size,
                              hipStream_t stream) {
  (void)in_sizes; (void)n_in; (void)out_size; (void)ws_size;
  const float* Hs    = (const float*)d_in[0];
  const float* Hw    = (const float*)d_in[1];
  const float* HSec  = (const float*)d_in[2];
  const int* w2s     = (const int*)d_in[3];
  const int* s2s     = (const int*)d_in[4];
  const int* S2s     = (const int*)d_in[5];
  const float* Ww_src = (const float*)d_in[6];
  const float* Ww_dst = (const float*)d_in[7];
  const float* aw_src = (const float*)d_in[8];
  const float* aw_dst = (const float*)d_in[9];
  const float* bw     = (const float*)d_in[10];
  const float* Wss    = (const float*)d_in[11];
  const float* as_src = (const float*)d_in[12];
  const float* as_dst = (const float*)d_in[13];
  const float* bs     = (const float*)d_in[14];
  const float* WS_src = (const float*)d_in[15];
  const float* WS_dst = (const float*)d_in[16];
  const float* aS_src = (const float*)d_in[17];
  const float* aS_dst = (const float*)d_in[18];
  const float* bS     = (const float*)d_in[19];
  const float* F1_w   = (const float*)d_in[20];
  const float* F1_b   = (const float*)d_in[21];
  const float* F2_w   = (const float*)d_in[22];
  const float* F2_b   = (const float*)d_in[23];
  const float* l1_w   = (const float*)d_in[24];
  const float* l1_b   = (const float*)d_in[25];
  const float* l2_w   = (const float*)d_in[26];
  const float* l2_b   = (const float*)d_in[27];
  float* outp = (float*)d_out;

  char* ws = (char*)d_ws;
  size_t cur_off = 0;
  auto alloc = [&](size_t bytes) -> char* {
    char* p = ws + cur_off;
    cur_off = (cur_off + bytes + 255) & ~(size_t)255;
    return p;
  };

  __bf16* Wt_w  = (__bf16*)alloc((size_t)5120 * 320 * 2);
  __bf16* Wt_s  = (__bf16*)alloc((size_t)5120 * 640 * 2);
  __bf16* Wt_S  = (__bf16*)alloc((size_t)5120 * 512 * 2);
  __bf16* WtF   = (__bf16*)alloc((size_t)5120 * 10240 * 2);  // F1, then reused for F2
  __bf16* Wt_l1 = (__bf16*)alloc((size_t)2048 * 5120 * 2);
  __bf16* Wt_l2 = (__bf16*)alloc((size_t)640 * 2048 * 2);
  __bf16* HS_bf = (__bf16*)alloc((size_t)1024 * 512 * 2);
  float* v_w = (float*)alloc(8 * 320 * 4);
  float* u_w = (float*)alloc(8 * 640 * 4);
  float* v_s = (float*)alloc(8 * 640 * 4);
  float* u_s = (float*)alloc(8 * 640 * 4);
  float* v_S = (float*)alloc(8 * 512 * 4);
  float* u_S = (float*)alloc(8 * 640 * 4);
  float* alw_s = (float*)alloc((size_t)kNW * 8 * 4);
  float* alw_d = (float*)alloc((size_t)kNS * 8 * 4);
  float* als_s = (float*)alloc((size_t)kNS * 8 * 4);
  float* als_d = (float*)alloc((size_t)kNS * 8 * 4);
  float* alS_s = (float*)alloc((size_t)kNSEC * 8 * 4);
  float* alS_d = (float*)alloc((size_t)kNS * 8 * 4);
  int* csr_i  = (int*)alloc((size_t)6 * kNS * 4);
  int* cnt_w = csr_i, *cnt_s = csr_i + kNS, *cnt_S = csr_i + 2 * kNS;
  int* cur_w = csr_i + 3 * kNS, *cur_s = csr_i + 4 * kNS, *cur_S = csr_i + 5 * kNS;
  int* off_w = (int*)alloc((size_t)(kNS + 1) * 4);
  int* off_s = (int*)alloc((size_t)(kNS + 1) * 4);
  int* off_S = (int*)alloc((size_t)(kNS + 1) * 4);
  int* ssrc_w = (int*)alloc((size_t)kEW * 4);
  int* ssrc_s = (int*)alloc((size_t)kES * 4);
  int* ssrc_S = (int*)alloc((size_t)kESEC * 4);
  float* hs_S = (float*)alloc((size_t)1024 * 5120 * 4);
  char* aggreg = alloc((size_t)kNS * 2560 * 2 + (size_t)kNS * 5120 * 2);
  __bf16* agg_w = (__bf16*)aggreg;
  __bf16* agg_s = (__bf16*)(aggreg + (size_t)kNS * 2560 * 2);
  __bf16* U1 = (__bf16*)aggreg;  // alias (agg dead by fusion1)
  __bf16* Uw = (__bf16*)alloc((size_t)kNS * 5120 * 2);
  __bf16* Us = (__bf16*)alloc((size_t)kNS * 5120 * 2);
  __bf16* US = (__bf16*)alloc((size_t)kNS * 5120 * 2);
  __bf16* U2 = Uw;  // alias (Uw dead after fusion1)
  __bf16* Tb = Us;  // alias (Us dead after fusion1)

  const dim3 b256(256);

  // 1) weight conversions/transposes
  conv_transpose<<<dim3(160, 10), b256, 0, stream>>>(Ww_src, 300, 5120, Wt_w, 320);
  conv_transpose<<<dim3(160, 20), b256, 0, stream>>>(Wss, 640, 5120, Wt_s, 640);
  conv_transpose<<<dim3(160, 16), b256, 0, stream>>>(WS_src, 512, 5120, Wt_S, 512);
  conv_transpose<<<dim3(160, 320), b256, 0, stream>>>(F1_w, 10240, 5120, WtF, 10240);
  conv_transpose<<<dim3(64, 160), b256, 0, stream>>>(l1_w, 5120, 2048, Wt_l1, 5120);
  conv_transpose<<<dim3(20, 64), b256, 0, stream>>>(l2_w, 2048, 640, Wt_l2, 2048);
  conv_bf<<<(1024 * 512 + 255) / 256, b256, 0, stream>>>(HSec, HS_bf, (long)1024 * 512);

  // 2) per-head attention vectors
  head_vecs<<<(8 * 320 + 255) / 256, b256, 0, stream>>>(Ww_src, aw_src, v_w, 300, 320);
  head_vecs<<<(8 * 640 + 255) / 256, b256, 0, stream>>>(Ww_dst, aw_dst, u_w, 640, 640);
  head_vecs<<<(8 * 640 + 255) / 256, b256, 0, stream>>>(Wss, as_src, v_s, 640, 640);
  head_vecs<<<(8 * 640 + 255) / 256, b256, 0, stream>>>(Wss, as_dst, u_s, 640, 640);
  head_vecs<<<(8 * 512 + 255) / 256, b256, 0, stream>>>(WS_src, aS_src, v_S, 512, 512);
  head_vecs<<<(8 * 640 + 255) / 256, b256, 0, stream>>>(WS_dst, aS_dst, u_S, 640, 640);

  // 3) attention logits
  att_logits<<<(kNW + 3) / 4, b256, 0, stream>>>(Hw, 300, 300, v_w, 320, alw_s, kNW);
  att_logits<<<(kNS + 3) / 4, b256, 0, stream>>>(Hs, 640, 640, u_w, 640, alw_d, kNS);
  att_logits<<<(kNS + 3) / 4, b256, 0, stream>>>(Hs, 640, 640, v_s, 640, als_s, kNS);
  att_logits<<<(kNS + 3) / 4, b256, 0, stream>>>(Hs, 640, 640, u_s, 640, als_d, kNS);
  att_logits<<<(kNSEC + 3) / 4, b256, 0, stream>>>(HSec, 512, 512, v_S, 512, alS_s, kNSEC);
  att_logits<<<(kNS + 3) / 4, b256, 0, stream>>>(Hs, 640, 640, u_S, 640, alS_d, kNS);

  // 4) CSR build (per layer)
  hipMemsetAsync(csr_i, 0, (size_t)6 * kNS * 4, stream);
  edge_count<<<(kEW + 255) / 256, b256, 0, stream>>>(w2s + kEW, kEW, cnt_w);
  edge_count<<<(kES + 255) / 256, b256, 0, stream>>>(s2s + kES, kES, cnt_s);
  edge_count<<<(kESEC + 255) / 256, b256, 0, stream>>>(S2s + kESEC, kESEC, cnt_S);
  scan_off<<<1, 1024, 0, stream>>>(cnt_w, off_w);
  scan_off<<<1, 1024, 0, stream>>>(cnt_s, off_s);
  scan_off<<<1, 1024, 0, stream>>>(cnt_S, off_S);
  edge_fill<<<(kEW + 255) / 256, b256, 0, stream>>>(w2s, w2s + kEW, kEW, off_w, cur_w, ssrc_w);
  edge_fill<<<(kES + 255) / 256, b256, 0, stream>>>(s2s, s2s + kES, kES, off_s, cur_s, ssrc_s);
  edge_fill<<<(kESEC + 255) / 256, b256, 0, stream>>>(S2s, S2s + kESEC, kESEC, off_S, cur_S, ssrc_S);

  // 5) section source transform: hs_S = HS @ WS_src  (f32 out)
  gemm_bt<0><<<dim3(40, 8, 1), b256, 0, stream>>>(
      HS_bf, 512, nullptr, 1 << 30, Wt_S, 512, 512,
      hs_S, 5120, nullptr, nullptr, nullptr, 0, nullptr, 0, 0, 0, 0, 0);

  // 6) aggregations
  gat_agg<320, 300, false, false><<<kNS, b256, 0, stream>>>(off_w, ssrc_w, alw_s, alw_d, Hw, 300, agg_w, 2560, nullptr);
  gat_agg<640, 640, false, false><<<kNS, b256, 0, stream>>>(off_s, ssrc_s, als_s, als_d, Hs, 640, agg_s, 5120, nullptr);
  gat_agg<640, 640, true, true><<<kNS, b256, 0, stream>>>(off_S, ssrc_S, alS_s, alS_d, hs_S, 5120, US, 5120, bS);

  // 7) per-head GAT output GEMMs (+bias +ELU)
  gemm_bt<1><<<dim3(5, 64, 8), b256, 0, stream>>>(
      agg_w, 2560, nullptr, 1 << 30, Wt_w, 320, 320,
      Uw, 5120, bw, nullptr, nullptr, 0, nullptr, 0, 320, (long)640 * 320, 640, 640);
  gemm_bt<1><<<dim3(5, 64, 8), b256, 0, stream>>>(
      agg_s, 5120, nullptr, 1 << 30, Wt_s, 640, 640,
      Us, 5120, bs, nullptr, nullptr, 0, nullptr, 0, 640, (long)640 * 640, 640, 640);

  // 8) fusion 1 (256^2 8-phase): U1 = z*Uw + (1-z)*Us
  gemm256<2><<<dim3(640), dim3(512), 0, stream>>>(
      Uw, 5120, Us, 5120, WtF, 10240, 10240,
      U1, 5120, F1_b, Uw, Us, 5120, 20);

  // 9) convert F2 into the (now free) WtF buffer, then fusion 2 -> U2
  conv_transpose<<<dim3(160, 320), b256, 0, stream>>>(F2_w, 10240, 5120, WtF, 10240);
  gemm256<2><<<dim3(640), dim3(512), 0, stream>>>(
      U1, 5120, US, 5120, WtF, 10240, 10240,
      U2, 5120, F2_b, U1, US, 5120, 20);

  // 10) FFN
  gemm256<3><<<dim3(256), dim3(512), 0, stream>>>(
      U2, 5120, nullptr, 1 << 30, Wt_l1, 5120, 5120,
      Tb, 2048, l1_b, nullptr, nullptr, 0, 8);
  gemm_bt<4><<<dim3(5, 64, 1), b256, 0, stream>>>(
      Tb, 2048, nullptr, 1 << 30, Wt_l2, 2048, 2048,
      outp, 640, l2_b, nullptr, nullptr, 0, Hs, 640, 0, 0, 0, 0);
}